// Round 6
// baseline (127.169 us; speedup 1.0000x reference)
//
#include <hip/hip_runtime.h>
#include <math.h>

#define NN 1024
#define B_C 64
#define L_C 160000
#define T_C 622
#define F_C 513
#define TT 16
#define NTILE ((T_C + TT - 1) / TT)   // 39
#define WIN_MIN_C (1024.0f / 20.0f)
#define WIN_MAX_C 1024.0f
#define TWO_PI 6.28318530717958647692f

__device__ __forceinline__ int brev6(int x) {
    return ((x & 1) << 5) | ((x & 2) << 3) | ((x & 4) << 1) |
           ((x & 8) >> 1) | ((x & 16) >> 3) | ((x & 32) >> 5);
}

typedef unsigned uv2 __attribute__((ext_vector_type(2)));

// ---- lane-exchange helpers: VALU-rate (permlane/DPP) where possible ----
__device__ __forceinline__ float lane_xor32(float v, int l) {
#if __has_builtin(__builtin_amdgcn_permlane32_swap)
    uv2 r = __builtin_amdgcn_permlane32_swap(__float_as_uint(v), __float_as_uint(v),
                                             false, false);
    return __uint_as_float((l & 32) ? r.x : r.y);
#else
    return __shfl_xor(v, 32, 64);
#endif
}
__device__ __forceinline__ float lane_xor16(float v, int l) {
#if __has_builtin(__builtin_amdgcn_permlane16_swap)
    uv2 r = __builtin_amdgcn_permlane16_swap(__float_as_uint(v), __float_as_uint(v),
                                             false, false);
    return __uint_as_float((l & 16) ? r.x : r.y);
#else
    return __shfl_xor(v, 16, 64);
#endif
}
__device__ __forceinline__ float lane_xor8(float v) {   // row_ror:8 == xor8
    return __int_as_float(__builtin_amdgcn_update_dpp(
        __float_as_int(v), __float_as_int(v), 0x128, 0xF, 0xF, false));
}
__device__ __forceinline__ float lane_xor4(float v) {   // ds_swizzle xor4
    return __int_as_float(__builtin_amdgcn_ds_swizzle(__float_as_int(v), 0x101F));
}
__device__ __forceinline__ float lane_xor2(float v) {   // quad_perm [2,3,0,1]
    return __int_as_float(__builtin_amdgcn_update_dpp(
        __float_as_int(v), __float_as_int(v), 0x4E, 0xF, 0xF, false));
}
__device__ __forceinline__ float lane_xor1(float v) {   // quad_perm [1,0,3,2]
    return __int_as_float(__builtin_amdgcn_update_dpp(
        __float_as_int(v), __float_as_int(v), 0xB1, 0xF, 0xF, false));
}
__device__ __forceinline__ float lane_mirror16(float v) { // row_mirror == xor15
    return __int_as_float(__builtin_amdgcn_update_dpp(
        __float_as_int(v), __float_as_int(v), 0x140, 0xF, 0xF, false));
}
__device__ __forceinline__ float lane_xor63(float v, int l) {
    return lane_xor32(lane_xor16(lane_mirror16(v), l), l);  // 15^16^32 = 63
}
__device__ __forceinline__ float fast_sqrtf(float x) {
#if __has_builtin(__builtin_amdgcn_sqrtf)
    return __builtin_amdgcn_sqrtf(x);
#else
    return sqrtf(x);
#endif
}

// ---------------- Kernel A: per-frame normalized Hann taps ----------------
__global__ __launch_bounds__(256) void win_kernel(
    const float* __restrict__ win_length,
    const float* __restrict__ strides,
    const float* __restrict__ win_pow,
    float* __restrict__ tap)   // [T_C][NN]
{
    const int t = blockIdx.x;
    const int tid = threadIdx.x;

    const float wl = fminf(fmaxf(win_length[0], WIN_MIN_C), WIN_MAX_C);
    const float st = fminf(fmaxf(strides[0], 0.0f), WIN_MAX_C);
    const float wp = win_pow[0];

    const float frame = (float)t * st;
    const float frac = frame - floorf(frame);

    const float hi = ceilf(((float)NN - 1.0f + wl) * 0.5f);
    const float lo = floorf(((float)NN - 1.0f - wl) * 0.5f);
    const float off = (wl - (float)NN + 1.0f) * 0.5f;
    const float inv_wl = 1.0f / wl;

    __shared__ float s_tap[NN];
    __shared__ float s_red[256];

    float local = 0.0f;
    for (int n = tid; n < NN; n += 256) {
        float base = (float)n - frac;
        float v = 0.5f - 0.5f * cosf(TWO_PI * (base + off) * inv_wl);
        if (base >= hi || base <= lo) v = 0.0f;
        s_tap[n] = v;
        local += v;
    }
    s_red[tid] = local;
    __syncthreads();
    for (int s = 128; s > 0; s >>= 1) {
        if (tid < s) s_red[tid] += s_red[tid + s];
        __syncthreads();
    }
    const float inv_sum = 1.0f / s_red[0];
    const bool pow_one = (wp == 1.0f);
    for (int n = tid; n < NN; n += 256) {
        float v = s_tap[n] * inv_sum;
        if (!pow_one) v = powf(v, wp);
        tap[t * NN + n] = v;
    }
}

// --- Kernel B: 8 waves/block, wave-per-packed-FFT, registers + permlane ---
__global__ __launch_bounds__(512, 4) void fftw_kernel(
    const float* __restrict__ x,        // [B_C][L_C]
    const float* __restrict__ strides,
    const float* __restrict__ tap,      // [T_C][NN]
    float* __restrict__ out)            // [B_C][F_C][T_C]
{
    const int tile = blockIdx.x % NTILE;
    const int b = blockIdx.x / NTILE;
    const int t0 = tile * TT;
    const int tid = threadIdx.x;
    const int w = tid >> 6;      // wave id 0..7 = frame pair
    const int l = tid & 63;      // lane

    const float st = fminf(fmaxf(strides[0], 0.0f), WIN_MAX_C);
    const float* xb = x + (size_t)b * L_C;

    __shared__ float mag2[F_C][TT + 2];   // [f][t-within-tile], float2-friendly

    const int bl = brev6(l);
    const int l2 = brev6((64 - bl) & 63);   // unpack partner lane for k1==0 reg

    constexpr int BR4[16]     = {0,8,4,12,2,10,6,14,1,9,5,13,3,11,7,15};
    constexpr int PARTNER[16] = {0,1,3,2,7,6,5,4,15,14,13,12,11,10,9,8};
    constexpr float C16[8] = {1.0f, 0.92387953251f, 0.70710678119f, 0.38268343236f,
                              0.0f, -0.38268343236f, -0.70710678119f, -0.92387953251f};
    constexpr float S16[8] = {0.0f, -0.38268343236f, -0.70710678119f, -0.92387953251f,
                              -1.0f, -0.92387953251f, -0.70710678119f, -0.38268343236f};

    const int jp = w;                   // pair index 0..7
    const int tA = t0 + 2 * jp;
    const int tB = tA + 1;
    const bool hasA = (tA < T_C);
    const bool hasB = (tB < T_C);
    const int idxA = hasA ? (int)floorf((float)tA * st) : 0;
    const int idxB = hasB ? (int)floorf((float)tB * st) : 0;
    const float* tpA = tap + (size_t)tA * NN;
    const float* tpB = tap + (size_t)tB * NN;

    float vr[16], vi[16];

    // ---- load + taper: frame A -> re, frame B -> im; element n = 64*r + l
#pragma unroll
    for (int r = 0; r < 16; ++r) {
        const int n = r * 64 + l;
        float a = 0.0f, bb = 0.0f;
        if (hasA) {
            int ia = idxA + n;
            a = (ia >= 0 && ia < L_C) ? xb[ia] * tpA[n] : 0.0f;
        }
        if (hasB) {
            int ib = idxB + n;
            bb = (ib >= 0 && ib < L_C) ? xb[ib] * tpB[n] : 0.0f;
        }
        vr[r] = a;
        vi[r] = bb;
    }

    // ---- 16-point DIF FFT over registers (output i holds k1 = BR4[i])
#pragma unroll
    for (int s = 0; s < 4; ++s) {
        const int half = (16 >> s) >> 1;
#pragma unroll
        for (int b0 = 0; b0 < 16; b0 += (16 >> s)) {
#pragma unroll
            for (int j = 0; j < 8; ++j) {
                if (j < half) {
                    const int i0 = b0 + j, i1 = b0 + j + half;
                    const float ur = vr[i0], ui = vi[i0];
                    const float wr = vr[i1], wi = vi[i1];
                    vr[i0] = ur + wr; vi[i0] = ui + wi;
                    const float dr = ur - wr, di = ui - wi;
                    const float c = C16[j << s], ss = S16[j << s];
                    vr[i1] = dr * c - di * ss;
                    vi[i1] = dr * ss + di * c;
                }
            }
        }
    }

    // ---- twiddle W_1024^(l * k1) via 1 sincos + complex recurrence
    {
        float w1i, w1r;
        __sincosf(-(TWO_PI / 1024.0f) * (float)l, &w1i, &w1r);
        float cwr = w1r, cwi = w1i;                 // w^1
#pragma unroll
        for (int k1 = 1; k1 < 16; ++k1) {
            const int i = BR4[k1];                  // reg holding this k1
            const float ar = vr[i], ai = vi[i];
            vr[i] = ar * cwr - ai * cwi;
            vi[i] = ar * cwi + ai * cwr;
            const float nr = cwr * w1r - cwi * w1i;
            const float ni = cwr * w1i + cwi * w1r;
            cwr = nr; cwi = ni;
        }
    }

    // ---- 64-point DIF FFT across lanes; exchanges via permlane/DPP
#pragma unroll
    for (int s = 0; s < 6; ++s) {
        const int half = 32 >> s;
        const bool low = (l & (2 * half - 1)) < half;
        const float sgn = low ? 1.0f : -1.0f;
        const int j = l & (half - 1);
        float sv, cv;
        __sincosf(-(TWO_PI * (float)j) / (float)(2 * half), &sv, &cv);
        const float tc = low ? 1.0f : cv;
        const float ts = low ? 0.0f : sv;
#pragma unroll
        for (int i = 0; i < 16; ++i) {
            float pr, pi;
            if (s == 0)      { pr = lane_xor32(vr[i], l); pi = lane_xor32(vi[i], l); }
            else if (s == 1) { pr = lane_xor16(vr[i], l); pi = lane_xor16(vi[i], l); }
            else if (s == 2) { pr = lane_xor8(vr[i]);     pi = lane_xor8(vi[i]); }
            else if (s == 3) { pr = lane_xor4(vr[i]);     pi = lane_xor4(vi[i]); }
            else if (s == 4) { pr = lane_xor2(vr[i]);     pi = lane_xor2(vi[i]); }
            else             { pr = lane_xor1(vr[i]);     pi = lane_xor1(vi[i]); }
            const float sr = fmaf(sgn, vr[i], pr);     // low: v+p ; high: p-v
            const float si = fmaf(sgn, vi[i], pi);
            vr[i] = sr * tc - si * ts;
            vi[i] = sr * ts + si * tc;
        }
    }
    // now (lane l, reg i) holds X[k], k = BR4[i] + 16*brev6(l)

    // ---- conjugate-symmetry unpack + magnitudes -> mag2 LDS
#pragma unroll
    for (int i = 0; i < 16; ++i) {
        const int k1 = BR4[i];
        float yr, yi;
        if (k1 == 0) {
            yr = __shfl(vr[0], l2, 64);
            yi = __shfl(vi[0], l2, 64);
        } else {
            yr = lane_xor63(vr[PARTNER[i]], l);
            yi = lane_xor63(vi[PARTNER[i]], l);
        }
        const int k = k1 + 16 * bl;
        if (k <= 512) {
            const float zr = vr[i], zi = vi[i];
            const float sa = zr + yr, sb = zi - yi;     // 2*Re/Im of frame A
            const float ua = zi + yi, ub = yr - zr;     // 2*Re/Im of frame B
            const float magA = 0.5f * fast_sqrtf(sa * sa + sb * sb);
            const float magB = 0.5f * fast_sqrtf(ua * ua + ub * ub);
            if (hasA && hasB) {
                *(float2*)&mag2[k][2 * jp] = make_float2(magA, magB);
            } else if (hasA) {
                mag2[k][2 * jp] = magA;
            }
        }
    }

    __syncthreads();

    // ---- coalesced write-out: rows of 16 consecutive t per f
    for (int e = tid; e < F_C * TT; e += 512) {
        const int f = e >> 4;
        const int tt = e & 15;
        const int t = t0 + tt;
        if (t < T_C)
            out[((size_t)b * F_C + f) * T_C + t] = mag2[f][tt];
    }
}

extern "C" void kernel_launch(void* const* d_in, const int* in_sizes, int n_in,
                              void* d_out, int out_size, void* d_ws, size_t ws_size,
                              hipStream_t stream) {
    const float* x   = (const float*)d_in[0];
    const float* wl  = (const float*)d_in[1];
    const float* st  = (const float*)d_in[2];
    const float* wp  = (const float*)d_in[3];
    float* out = (float*)d_out;
    float* tap = (float*)d_ws;   // T_C*NN floats ~ 2.55 MB

    win_kernel<<<dim3(T_C), dim3(256), 0, stream>>>(wl, st, wp, tap);
    fftw_kernel<<<dim3(B_C * NTILE), dim3(512), 0, stream>>>(x, st, tap, out);
}

// Round 7
// 103.096 us; speedup vs baseline: 1.2335x; 1.2335x over previous
//
#include <hip/hip_runtime.h>
#include <math.h>

#define NN 1024
#define B_C 64
#define L_C 160000
#define T_C 622
#define F_C 513
#define TT 16
#define NTILE ((T_C + TT - 1) / TT)   // 39
#define WIN_MIN_C (1024.0f / 20.0f)
#define WIN_MAX_C 1024.0f
#define TWO_PI 6.28318530717958647692f

__device__ __forceinline__ int brev6(int x) {
    return ((x & 1) << 5) | ((x & 2) << 3) | ((x & 4) << 1) |
           ((x & 8) >> 1) | ((x & 16) >> 3) | ((x & 32) >> 5);
}

typedef unsigned uv2 __attribute__((ext_vector_type(2)));

// ---- lane-exchange helpers: VALU-rate (permlane/DPP) where possible ----
__device__ __forceinline__ float lane_xor32(float v, int l) {
#if __has_builtin(__builtin_amdgcn_permlane32_swap)
    uv2 r = __builtin_amdgcn_permlane32_swap(__float_as_uint(v), __float_as_uint(v),
                                             false, false);
    return __uint_as_float((l & 32) ? r.x : r.y);
#else
    return __shfl_xor(v, 32, 64);
#endif
}
__device__ __forceinline__ float lane_xor16(float v, int l) {
#if __has_builtin(__builtin_amdgcn_permlane16_swap)
    uv2 r = __builtin_amdgcn_permlane16_swap(__float_as_uint(v), __float_as_uint(v),
                                             false, false);
    return __uint_as_float((l & 16) ? r.x : r.y);
#else
    return __shfl_xor(v, 16, 64);
#endif
}
__device__ __forceinline__ float lane_xor8(float v) {   // row_ror:8 == xor8
    return __int_as_float(__builtin_amdgcn_update_dpp(
        __float_as_int(v), __float_as_int(v), 0x128, 0xF, 0xF, false));
}
__device__ __forceinline__ float lane_xor4(float v) {   // ds_swizzle xor4
    return __int_as_float(__builtin_amdgcn_ds_swizzle(__float_as_int(v), 0x101F));
}
__device__ __forceinline__ float lane_xor2(float v) {   // quad_perm [2,3,0,1]
    return __int_as_float(__builtin_amdgcn_update_dpp(
        __float_as_int(v), __float_as_int(v), 0x4E, 0xF, 0xF, false));
}
__device__ __forceinline__ float lane_xor1(float v) {   // quad_perm [1,0,3,2]
    return __int_as_float(__builtin_amdgcn_update_dpp(
        __float_as_int(v), __float_as_int(v), 0xB1, 0xF, 0xF, false));
}
__device__ __forceinline__ float lane_mirror16(float v) { // row_mirror == xor15
    return __int_as_float(__builtin_amdgcn_update_dpp(
        __float_as_int(v), __float_as_int(v), 0x140, 0xF, 0xF, false));
}
__device__ __forceinline__ float lane_xor63(float v, int l) {
    return lane_xor32(lane_xor16(lane_mirror16(v), l), l);  // 15^16^32 = 63
}
__device__ __forceinline__ float fast_sqrtf(float x) {
#if __has_builtin(__builtin_amdgcn_sqrtf)
    return __builtin_amdgcn_sqrtf(x);
#else
    return sqrtf(x);
#endif
}

// ---------------- Kernel A: per-frame normalized Hann taps ----------------
__global__ __launch_bounds__(256) void win_kernel(
    const float* __restrict__ win_length,
    const float* __restrict__ strides,
    const float* __restrict__ win_pow,
    float* __restrict__ tap)   // [T_C][NN]
{
    const int t = blockIdx.x;
    const int tid = threadIdx.x;

    const float wl = fminf(fmaxf(win_length[0], WIN_MIN_C), WIN_MAX_C);
    const float st = fminf(fmaxf(strides[0], 0.0f), WIN_MAX_C);
    const float wp = win_pow[0];

    const float frame = (float)t * st;
    const float frac = frame - floorf(frame);

    const float hi = ceilf(((float)NN - 1.0f + wl) * 0.5f);
    const float lo = floorf(((float)NN - 1.0f - wl) * 0.5f);
    const float off = (wl - (float)NN + 1.0f) * 0.5f;
    const float inv_wl = 1.0f / wl;

    __shared__ float s_tap[NN];
    __shared__ float s_red[256];

    float local = 0.0f;
    for (int n = tid; n < NN; n += 256) {
        float base = (float)n - frac;
        float v = 0.5f - 0.5f * cosf(TWO_PI * (base + off) * inv_wl);
        if (base >= hi || base <= lo) v = 0.0f;
        s_tap[n] = v;
        local += v;
    }
    s_red[tid] = local;
    __syncthreads();
    for (int s = 128; s > 0; s >>= 1) {
        if (tid < s) s_red[tid] += s_red[tid + s];
        __syncthreads();
    }
    const float inv_sum = 1.0f / s_red[0];
    const bool pow_one = (wp == 1.0f);
    for (int n = tid; n < NN; n += 256) {
        float v = s_tap[n] * inv_sum;
        if (!pow_one) v = powf(v, wp);
        tap[t * NN + n] = v;
    }
}

// --- Kernel B: 8 waves/block, wave-per-packed-FFT, registers + permlane ---
__global__ __launch_bounds__(512, 4) void fftw_kernel(
    const float* __restrict__ x,        // [B_C][L_C]
    const float* __restrict__ strides,
    const float* __restrict__ tap,      // [T_C][NN]
    float* __restrict__ out)            // [B_C][F_C][T_C]
{
    const int tile = blockIdx.x % NTILE;
    const int b = blockIdx.x / NTILE;
    const int t0 = tile * TT;
    const int tid = threadIdx.x;
    const int w = tid >> 6;      // wave id 0..7 = frame pair
    const int l = tid & 63;      // lane

    const float st = fminf(fmaxf(strides[0], 0.0f), WIN_MAX_C);
    const float* xb = x + (size_t)b * L_C;

    __shared__ float mag[TT][F_C + 16];   // 529-float rows: stride%32=17, coprime

    const int bl = brev6(l);
    const int l2 = brev6((64 - bl) & 63);   // unpack partner lane for k1==0 reg

    constexpr int BR4[16]     = {0,8,4,12,2,10,6,14,1,9,5,13,3,11,7,15};
    constexpr int PARTNER[16] = {0,1,3,2,7,6,5,4,15,14,13,12,11,10,9,8};
    constexpr float C16[8] = {1.0f, 0.92387953251f, 0.70710678119f, 0.38268343236f,
                              0.0f, -0.38268343236f, -0.70710678119f, -0.92387953251f};
    constexpr float S16[8] = {0.0f, -0.38268343236f, -0.70710678119f, -0.92387953251f,
                              -1.0f, -0.92387953251f, -0.70710678119f, -0.38268343236f};

    const int jp = w;                   // pair index 0..7
    const int tA = t0 + 2 * jp;
    const int tB = tA + 1;
    const bool hasA = (tA < T_C);
    const bool hasB = (tB < T_C);
    const int idxA = hasA ? (int)floorf((float)tA * st) : 0;
    const int idxB = hasB ? (int)floorf((float)tB * st) : 0;
    const float* tpA = tap + (size_t)tA * NN;
    const float* tpB = tap + (size_t)tB * NN;

    float vr[16], vi[16];

    // ---- load + taper: frame A -> re, frame B -> im; element n = 64*r + l
#pragma unroll
    for (int r = 0; r < 16; ++r) {
        const int n = r * 64 + l;
        float a = 0.0f, bb = 0.0f;
        if (hasA) {
            int ia = idxA + n;
            a = (ia >= 0 && ia < L_C) ? xb[ia] * tpA[n] : 0.0f;
        }
        if (hasB) {
            int ib = idxB + n;
            bb = (ib >= 0 && ib < L_C) ? xb[ib] * tpB[n] : 0.0f;
        }
        vr[r] = a;
        vi[r] = bb;
    }

    // ---- 16-point DIF FFT over registers (output i holds k1 = BR4[i])
#pragma unroll
    for (int s = 0; s < 4; ++s) {
        const int half = (16 >> s) >> 1;
#pragma unroll
        for (int b0 = 0; b0 < 16; b0 += (16 >> s)) {
#pragma unroll
            for (int j = 0; j < 8; ++j) {
                if (j < half) {
                    const int i0 = b0 + j, i1 = b0 + j + half;
                    const float ur = vr[i0], ui = vi[i0];
                    const float wr = vr[i1], wi = vi[i1];
                    vr[i0] = ur + wr; vi[i0] = ui + wi;
                    const float dr = ur - wr, di = ui - wi;
                    const float c = C16[j << s], ss = S16[j << s];
                    vr[i1] = dr * c - di * ss;
                    vi[i1] = dr * ss + di * c;
                }
            }
        }
    }

    // ---- twiddle W_1024^(l * k1) via 1 sincos + complex recurrence
    {
        float w1i, w1r;
        __sincosf(-(TWO_PI / 1024.0f) * (float)l, &w1i, &w1r);
        float cwr = w1r, cwi = w1i;                 // w^1
#pragma unroll
        for (int k1 = 1; k1 < 16; ++k1) {
            const int i = BR4[k1];                  // reg holding this k1
            const float ar = vr[i], ai = vi[i];
            vr[i] = ar * cwr - ai * cwi;
            vi[i] = ar * cwi + ai * cwr;
            const float nr = cwr * w1r - cwi * w1i;
            const float ni = cwr * w1i + cwi * w1r;
            cwr = nr; cwi = ni;
        }
    }

    // ---- 64-point DIF FFT across lanes; exchanges via permlane/DPP
#pragma unroll
    for (int s = 0; s < 6; ++s) {
        const int half = 32 >> s;
        const bool low = (l & (2 * half - 1)) < half;
        const float sgn = low ? 1.0f : -1.0f;
        const int j = l & (half - 1);
        float sv, cv;
        __sincosf(-(TWO_PI * (float)j) / (float)(2 * half), &sv, &cv);
        const float tc = low ? 1.0f : cv;
        const float ts = low ? 0.0f : sv;
#pragma unroll
        for (int i = 0; i < 16; ++i) {
            float pr, pi;
            if (s == 0)      { pr = lane_xor32(vr[i], l); pi = lane_xor32(vi[i], l); }
            else if (s == 1) { pr = lane_xor16(vr[i], l); pi = lane_xor16(vi[i], l); }
            else if (s == 2) { pr = lane_xor8(vr[i]);     pi = lane_xor8(vi[i]); }
            else if (s == 3) { pr = lane_xor4(vr[i]);     pi = lane_xor4(vi[i]); }
            else if (s == 4) { pr = lane_xor2(vr[i]);     pi = lane_xor2(vi[i]); }
            else             { pr = lane_xor1(vr[i]);     pi = lane_xor1(vi[i]); }
            const float sr = fmaf(sgn, vr[i], pr);     // low: v+p ; high: p-v
            const float si = fmaf(sgn, vi[i], pi);
            vr[i] = sr * tc - si * ts;
            vi[i] = sr * ts + si * tc;
        }
    }
    // now (lane l, reg i) holds X[k], k = BR4[i] + 16*brev6(l)

    // ---- conjugate-symmetry unpack + magnitudes -> mag LDS
#pragma unroll
    for (int i = 0; i < 16; ++i) {
        const int k1 = BR4[i];
        float yr, yi;
        if (k1 == 0) {
            yr = __shfl(vr[0], l2, 64);
            yi = __shfl(vi[0], l2, 64);
        } else {
            yr = lane_xor63(vr[PARTNER[i]], l);
            yi = lane_xor63(vi[PARTNER[i]], l);
        }
        const int k = k1 + 16 * bl;
        if (k <= 512) {
            const float zr = vr[i], zi = vi[i];
            const float sa = zr + yr, sb = zi - yi;     // 2*Re/Im of frame A
            const float ua = zi + yi, ub = yr - zr;     // 2*Re/Im of frame B
            const int ka = k + (k >> 5);
            if (hasA) mag[2 * jp][ka] = 0.5f * fast_sqrtf(sa * sa + sb * sb);
            if (hasB) mag[2 * jp + 1][ka] = 0.5f * fast_sqrtf(ua * ua + ub * ub);
        }
    }

    __syncthreads();

    // ---- coalesced write-out: rows of 16 consecutive t per f
    for (int e = tid; e < F_C * TT; e += 512) {
        const int f = e >> 4;
        const int tt = e & 15;
        const int t = t0 + tt;
        if (t < T_C)
            out[((size_t)b * F_C + f) * T_C + t] = mag[tt][f + (f >> 5)];
    }
}

extern "C" void kernel_launch(void* const* d_in, const int* in_sizes, int n_in,
                              void* d_out, int out_size, void* d_ws, size_t ws_size,
                              hipStream_t stream) {
    const float* x   = (const float*)d_in[0];
    const float* wl  = (const float*)d_in[1];
    const float* st  = (const float*)d_in[2];
    const float* wp  = (const float*)d_in[3];
    float* out = (float*)d_out;
    float* tap = (float*)d_ws;   // T_C*NN floats ~ 2.55 MB

    win_kernel<<<dim3(T_C), dim3(256), 0, stream>>>(wl, st, wp, tap);
    fftw_kernel<<<dim3(B_C * NTILE), dim3(512), 0, stream>>>(x, st, tap, out);
}

// Round 8
// 82.334 us; speedup vs baseline: 1.5445x; 1.2522x over previous
//
#include <hip/hip_runtime.h>
#include <math.h>

#define NN 1024
#define B_C 64
#define L_C 160000
#define T_C 622
#define F_C 513
#define TT 16
#define NTILE ((T_C + TT - 1) / TT)   // 39
#define WIN_MIN_C (1024.0f / 20.0f)
#define WIN_MAX_C 1024.0f
#define TWO_PI 6.28318530717958647692f

__device__ __forceinline__ int brev6(int x) {
    return ((x & 1) << 5) | ((x & 2) << 3) | ((x & 4) << 1) |
           ((x & 8) >> 1) | ((x & 16) >> 3) | ((x & 32) >> 5);
}

typedef unsigned uv2 __attribute__((ext_vector_type(2)));

// ---- lane-exchange helpers: VALU-rate (permlane/DPP) where possible ----
__device__ __forceinline__ float lane_xor32(float v, int l) {
#if __has_builtin(__builtin_amdgcn_permlane32_swap)
    uv2 r = __builtin_amdgcn_permlane32_swap(__float_as_uint(v), __float_as_uint(v),
                                             false, false);
    return __uint_as_float((l & 32) ? r.x : r.y);
#else
    return __shfl_xor(v, 32, 64);
#endif
}
__device__ __forceinline__ float lane_xor16(float v, int l) {
#if __has_builtin(__builtin_amdgcn_permlane16_swap)
    uv2 r = __builtin_amdgcn_permlane16_swap(__float_as_uint(v), __float_as_uint(v),
                                             false, false);
    return __uint_as_float((l & 16) ? r.x : r.y);
#else
    return __shfl_xor(v, 16, 64);
#endif
}
__device__ __forceinline__ float lane_xor8(float v) {   // row_ror:8 == xor8
    return __int_as_float(__builtin_amdgcn_update_dpp(
        __float_as_int(v), __float_as_int(v), 0x128, 0xF, 0xF, false));
}
__device__ __forceinline__ float lane_xor4(float v) {   // ds_swizzle xor4
    return __int_as_float(__builtin_amdgcn_ds_swizzle(__float_as_int(v), 0x101F));
}
__device__ __forceinline__ float lane_xor2(float v) {   // quad_perm [2,3,0,1]
    return __int_as_float(__builtin_amdgcn_update_dpp(
        __float_as_int(v), __float_as_int(v), 0x4E, 0xF, 0xF, false));
}
__device__ __forceinline__ float lane_xor1(float v) {   // quad_perm [1,0,3,2]
    return __int_as_float(__builtin_amdgcn_update_dpp(
        __float_as_int(v), __float_as_int(v), 0xB1, 0xF, 0xF, false));
}
__device__ __forceinline__ float lane_mirror16(float v) { // row_mirror == xor15
    return __int_as_float(__builtin_amdgcn_update_dpp(
        __float_as_int(v), __float_as_int(v), 0x140, 0xF, 0xF, false));
}
__device__ __forceinline__ float lane_xor63(float v, int l) {
    return lane_xor32(lane_xor16(lane_mirror16(v), l), l);  // 15^16^32 = 63
}
__device__ __forceinline__ float fast_sqrtf(float x) {
#if __has_builtin(__builtin_amdgcn_sqrtf)
    return __builtin_amdgcn_sqrtf(x);
#else
    return sqrtf(x);
#endif
}

// ---------------- Kernel A: per-frame normalized Hann taps ----------------
__global__ __launch_bounds__(256) void win_kernel(
    const float* __restrict__ win_length,
    const float* __restrict__ strides,
    const float* __restrict__ win_pow,
    float* __restrict__ tap)   // [T_C][NN]
{
    const int t = blockIdx.x;
    const int tid = threadIdx.x;

    const float wl = fminf(fmaxf(win_length[0], WIN_MIN_C), WIN_MAX_C);
    const float st = fminf(fmaxf(strides[0], 0.0f), WIN_MAX_C);
    const float wp = win_pow[0];

    const float frame = (float)t * st;
    const float frac = frame - floorf(frame);

    const float hi = ceilf(((float)NN - 1.0f + wl) * 0.5f);
    const float lo = floorf(((float)NN - 1.0f - wl) * 0.5f);
    const float off = (wl - (float)NN + 1.0f) * 0.5f;
    const float inv_wl = 1.0f / wl;

    __shared__ float s_tap[NN];
    __shared__ float s_red[256];

    float local = 0.0f;
    for (int n = tid; n < NN; n += 256) {
        float base = (float)n - frac;
        float v = 0.5f - 0.5f * cosf(TWO_PI * (base + off) * inv_wl);
        if (base >= hi || base <= lo) v = 0.0f;
        s_tap[n] = v;
        local += v;
    }
    s_red[tid] = local;
    __syncthreads();
    for (int s = 128; s > 0; s >>= 1) {
        if (tid < s) s_red[tid] += s_red[tid + s];
        __syncthreads();
    }
    const float inv_sum = 1.0f / s_red[0];
    const bool pow_one = (wp == 1.0f);
    for (int n = tid; n < NN; n += 256) {
        float v = s_tap[n] * inv_sum;
        if (!pow_one) v = powf(v, wp);
        tap[t * NN + n] = v;
    }
}

// --- Kernel B: 8 waves/block, wave-per-packed-FFT, registers + permlane ---
__global__ __launch_bounds__(512, 4) void fftw_kernel(
    const float* __restrict__ x,        // [B_C][L_C]
    const float* __restrict__ strides,
    const float* __restrict__ tap,      // [T_C][NN]
    float* __restrict__ out)            // [B_C][F_C][T_C]
{
    const int tile = blockIdx.x % NTILE;
    const int b = blockIdx.x / NTILE;
    const int t0 = tile * TT;
    const int tid = threadIdx.x;
    const int w = tid >> 6;      // wave id 0..7 = frame pair
    const int l = tid & 63;      // lane

    const float st = fminf(fmaxf(strides[0], 0.0f), WIN_MAX_C);
    const float* xb = x + (size_t)b * L_C;

    __shared__ float mag[TT][F_C + 16];   // 529-float rows: stride%32=17, coprime

    const int bl = brev6(l);
    const int l2 = brev6((64 - bl) & 63);   // unpack partner lane for k1==0 reg

    constexpr int BR4[16]     = {0,8,4,12,2,10,6,14,1,9,5,13,3,11,7,15};
    constexpr int PARTNER[16] = {0,1,3,2,7,6,5,4,15,14,13,12,11,10,9,8};
    constexpr float C16[8] = {1.0f, 0.92387953251f, 0.70710678119f, 0.38268343236f,
                              0.0f, -0.38268343236f, -0.70710678119f, -0.92387953251f};
    constexpr float S16[8] = {0.0f, -0.38268343236f, -0.70710678119f, -0.92387953251f,
                              -1.0f, -0.92387953251f, -0.70710678119f, -0.38268343236f};

    const int jp = w;                   // pair index 0..7
    const int tA = t0 + 2 * jp;
    const int tB = tA + 1;
    const bool hasA = (tA < T_C);
    const bool hasB = (tB < T_C);
    const int idxA = hasA ? (int)floorf((float)tA * st) : 0;
    const int idxB = hasB ? (int)floorf((float)tB * st) : 0;
    const float* tpA = tap + (size_t)tA * NN;
    const float* tpB = tap + (size_t)tB * NN;

    float vr[16], vi[16];

    // ---- load + taper: frame A -> re, frame B -> im; element n = 64*r + l
    // Wave-uniform fast path: whole frame in-bounds -> no per-element checks.
    const bool okA = hasA && (idxA >= 0) && (idxA + NN <= L_C);
    const bool okB = hasB && (idxB >= 0) && (idxB + NN <= L_C);
    if (okA && okB) {
#pragma unroll
        for (int r = 0; r < 16; ++r) {
            const int n = r * 64 + l;
            vr[r] = xb[idxA + n] * tpA[n];
            vi[r] = xb[idxB + n] * tpB[n];
        }
    } else {
#pragma unroll
        for (int r = 0; r < 16; ++r) {
            const int n = r * 64 + l;
            float a = 0.0f, bb = 0.0f;
            if (hasA) {
                int ia = idxA + n;
                a = (ia >= 0 && ia < L_C) ? xb[ia] * tpA[n] : 0.0f;
            }
            if (hasB) {
                int ib = idxB + n;
                bb = (ib >= 0 && ib < L_C) ? xb[ib] * tpB[n] : 0.0f;
            }
            vr[r] = a;
            vi[r] = bb;
        }
    }

    // ---- 16-point DIF FFT over registers (output i holds k1 = BR4[i])
#pragma unroll
    for (int s = 0; s < 4; ++s) {
        const int half = (16 >> s) >> 1;
#pragma unroll
        for (int b0 = 0; b0 < 16; b0 += (16 >> s)) {
#pragma unroll
            for (int j = 0; j < 8; ++j) {
                if (j < half) {
                    const int i0 = b0 + j, i1 = b0 + j + half;
                    const float ur = vr[i0], ui = vi[i0];
                    const float wr = vr[i1], wi = vi[i1];
                    vr[i0] = ur + wr; vi[i0] = ui + wi;
                    const float dr = ur - wr, di = ui - wi;
                    const float c = C16[j << s], ss = S16[j << s];
                    vr[i1] = dr * c - di * ss;
                    vi[i1] = dr * ss + di * c;
                }
            }
        }
    }

    // ---- twiddle W_1024^(l * k1): powers via doubling tree (log-depth, ILP)
    {
        float c1, s1;
        __sincosf(-(TWO_PI / 1024.0f) * (float)l, &s1, &c1);
        const float c2 = c1 * c1 - s1 * s1,  s2 = 2.0f * c1 * s1;
        const float c4 = c2 * c2 - s2 * s2,  s4 = 2.0f * c2 * s2;
        const float c8 = c4 * c4 - s4 * s4,  s8 = 2.0f * c4 * s4;
        const float c3 = c1 * c2 - s1 * s2,  s3 = c1 * s2 + s1 * c2;
        const float c5 = c1 * c4 - s1 * s4,  s5 = c1 * s4 + s1 * c4;
        const float c6 = c2 * c4 - s2 * s4,  s6 = c2 * s4 + s2 * c4;
        const float c7 = c3 * c4 - s3 * s4,  s7 = c3 * s4 + s3 * c4;
        const float c9  = c1 * c8 - s1 * s8, s9  = c1 * s8 + s1 * c8;
        const float c10 = c2 * c8 - s2 * s8, s10 = c2 * s8 + s2 * c8;
        const float c11 = c3 * c8 - s3 * s8, s11 = c3 * s8 + s3 * c8;
        const float c12 = c4 * c8 - s4 * s8, s12 = c4 * s8 + s4 * c8;
        const float c13 = c5 * c8 - s5 * s8, s13 = c5 * s8 + s5 * c8;
        const float c14 = c6 * c8 - s6 * s8, s14 = c6 * s8 + s6 * c8;
        const float c15 = c7 * c8 - s7 * s8, s15 = c7 * s8 + s7 * c8;
#define TW(K) { const int i_ = BR4[K]; const float ar = vr[i_], ai = vi[i_]; \
                vr[i_] = ar * c##K - ai * s##K; vi[i_] = ar * s##K + ai * c##K; }
        TW(1) TW(2) TW(3) TW(4) TW(5) TW(6) TW(7) TW(8)
        TW(9) TW(10) TW(11) TW(12) TW(13) TW(14) TW(15)
#undef TW
    }

    // ---- 64-point DIF FFT across lanes; batched exchange -> batched math
#pragma unroll
    for (int s = 0; s < 6; ++s) {
        const int half = 32 >> s;
        const bool low = (l & (2 * half - 1)) < half;
        const float sgn = low ? 1.0f : -1.0f;
        const int j = l & (half - 1);
        float sv, cv;
        __sincosf(-(TWO_PI * (float)j) / (float)(2 * half), &sv, &cv);
        const float tc = low ? 1.0f : cv;
        const float ts = low ? 0.0f : sv;
        float pr[16], pi[16];
#pragma unroll
        for (int i = 0; i < 16; ++i) {
            if (s == 0)      { pr[i] = lane_xor32(vr[i], l); pi[i] = lane_xor32(vi[i], l); }
            else if (s == 1) { pr[i] = lane_xor16(vr[i], l); pi[i] = lane_xor16(vi[i], l); }
            else if (s == 2) { pr[i] = lane_xor8(vr[i]);     pi[i] = lane_xor8(vi[i]); }
            else if (s == 3) { pr[i] = lane_xor4(vr[i]);     pi[i] = lane_xor4(vi[i]); }
            else if (s == 4) { pr[i] = lane_xor2(vr[i]);     pi[i] = lane_xor2(vi[i]); }
            else             { pr[i] = lane_xor1(vr[i]);     pi[i] = lane_xor1(vi[i]); }
        }
#pragma unroll
        for (int i = 0; i < 16; ++i) {
            const float sr = fmaf(sgn, vr[i], pr[i]);   // low: v+p ; high: p-v
            const float si = fmaf(sgn, vi[i], pi[i]);
            vr[i] = sr * tc - si * ts;
            vi[i] = sr * ts + si * tc;
        }
    }
    // now (lane l, reg i) holds X[k], k = BR4[i] + 16*brev6(l)

    // ---- conjugate-symmetry unpack: batched exchanges, then magnitudes
    {
        float yr[16], yi[16];
        yr[0] = __shfl(vr[0], l2, 64);
        yi[0] = __shfl(vi[0], l2, 64);
#pragma unroll
        for (int i = 1; i < 16; ++i) {
            yr[i] = lane_xor63(vr[PARTNER[i]], l);
            yi[i] = lane_xor63(vi[PARTNER[i]], l);
        }
#pragma unroll
        for (int i = 0; i < 16; ++i) {
            const int k = BR4[i] + 16 * bl;
            if (k <= 512) {
                const float sa = vr[i] + yr[i], sb = vi[i] - yi[i]; // 2*A
                const float ua = vi[i] + yi[i], ub = yr[i] - vr[i]; // 2*B
                const int ka = k + (k >> 5);
                if (hasA) mag[2 * jp][ka] = 0.5f * fast_sqrtf(sa * sa + sb * sb);
                if (hasB) mag[2 * jp + 1][ka] = 0.5f * fast_sqrtf(ua * ua + ub * ub);
            }
        }
    }

    __syncthreads();

    // ---- coalesced write-out: rows of 16 consecutive t per f
    for (int e = tid; e < F_C * TT; e += 512) {
        const int f = e >> 4;
        const int tt = e & 15;
        const int t = t0 + tt;
        if (t < T_C)
            out[((size_t)b * F_C + f) * T_C + t] = mag[tt][f + (f >> 5)];
    }
}

extern "C" void kernel_launch(void* const* d_in, const int* in_sizes, int n_in,
                              void* d_out, int out_size, void* d_ws, size_t ws_size,
                              hipStream_t stream) {
    const float* x   = (const float*)d_in[0];
    const float* wl  = (const float*)d_in[1];
    const float* st  = (const float*)d_in[2];
    const float* wp  = (const float*)d_in[3];
    float* out = (float*)d_out;
    float* tap = (float*)d_ws;   // T_C*NN floats ~ 2.55 MB

    win_kernel<<<dim3(T_C), dim3(256), 0, stream>>>(wl, st, wp, tap);
    fftw_kernel<<<dim3(B_C * NTILE), dim3(512), 0, stream>>>(x, st, tap, out);
}